// Round 9
// baseline (569.569 us; speedup 1.0000x reference)
//
#include <hip/hip_runtime.h>
#include <stdint.h>

typedef __attribute__((ext_vector_type(8))) short short8;
typedef __attribute__((ext_vector_type(4))) short short4v;
typedef __attribute__((ext_vector_type(4))) float floatx4;

__device__ __forceinline__ unsigned short f2bf(float x) {
  unsigned int u = __float_as_uint(x);
  u += 0x7fffu + ((u >> 16) & 1u);   // RNE
  return (unsigned short)(u >> 16);
}
__device__ __forceinline__ float bf2f(unsigned short b) {
  return __uint_as_float(((unsigned int)b) << 16);
}
// row swizzle: spreads same-column reads of consecutive rows across bank-quads.
__device__ __forceinline__ int sw3(int r) { return (r & 7) ^ (((r >> 3) & 1) * 3); }

// direct global->LDS (16B/lane). LDS dest = uniform base + lane*16 (linear);
// swizzle is applied on the per-lane GLOBAL address instead (m173 pattern).
__device__ __forceinline__ void gld16(const unsigned short* g, unsigned short* l) {
  __builtin_amdgcn_global_load_lds(
      (const __attribute__((address_space(1))) void*)g,
      (__attribute__((address_space(3))) void*)l, 16, 0, 0);
}

// ---- unified prologue: weight frags + h bf16 table, fully coalesced ----
// W1F/W2F B-frag layout: u=((k32*256+n)*4+kq)*8+j  holds W[k32*32+kq*8+j][n]
// W3F B-frag layout (N padded 2->16): u=(k32*64+L)*8+j holds W3[k32*32+(L>>4)*8+j][L&15] or 0
__global__ void prep_kernel(const float* __restrict__ h, const float* __restrict__ W1,
                            const float* __restrict__ W2, const float* __restrict__ W3,
                            unsigned short* __restrict__ HBF, unsigned short* __restrict__ W1F,
                            unsigned short* __restrict__ W2F, unsigned short* __restrict__ W3F,
                            int nh8) {
  const int t = threadIdx.x;
  int b = blockIdx.x;
  if (b < 512) {            // W1F: 131072 elems
    int u = b * 256 + t;
    int j = u & 7, kq = (u >> 3) & 3, n = (u >> 5) & 255, k32 = u >> 13;
    W1F[u] = f2bf(W1[(k32 * 32 + kq * 8 + j) * 256 + n]);
    return;
  }
  b -= 512;
  if (b < 256) {            // W2F: 65536 elems
    int u = b * 256 + t;
    int j = u & 7, kq = (u >> 3) & 3, n = (u >> 5) & 255, k32 = u >> 13;
    W2F[u] = f2bf(W2[(k32 * 32 + kq * 8 + j) * 256 + n]);
    return;
  }
  b -= 256;
  if (b < 16) {             // W3F: 4096 elems
    int u = b * 256 + t;
    int j = u & 7, L = (u >> 3) & 63, k32 = u >> 9;
    int n = L & 15, kq = L >> 4;
    W3F[u] = (n < 2) ? f2bf(W3[(k32 * 32 + kq * 8 + j) * 2 + n]) : (unsigned short)0;
    return;
  }
  b -= 16;
  int u = b * 256 + t;      // hcvt: 2x float4 -> 1x short8 (16B stores)
  if (u < nh8) {
    const float4* h4 = (const float4*)h;
    float4 v0 = h4[u * 2], v1 = h4[u * 2 + 1];
    short8 s;
    s[0] = (short)f2bf(v0.x); s[1] = (short)f2bf(v0.y);
    s[2] = (short)f2bf(v0.z); s[3] = (short)f2bf(v0.w);
    s[4] = (short)f2bf(v1.x); s[5] = (short)f2bf(v1.y);
    s[6] = (short)f2bf(v1.z); s[7] = (short)f2bf(v1.w);
    ((short8*)HBF)[u] = s;
  }
}

// ---- main kernel: R3 dual-buffer pipelined K-split, 32x128 wave tiles ----
// 4 waves / 256 threads / __launch_bounds__(256,2) (the proven zero-spill
// config, 291 us). Change vs R3: per-wave output re-tiled 64x64 -> 32x128
// (wave w: rows (w&1)*32..+31, cols (w>>1)*128..+127). A-fragment reuse
// doubles (each af feeds 8 MFMAs, not 4) -> per-kstep ds_read_b128 per CU
// drops 32 -> 16 (384 -> 192 cyc vs ~310 cyc MFMA issue): removes the
// LDS-read-issue bottleneck R6 exposed (conflicts 1.36e7 scaled with
// A-reads). acc[2][8]=64 AGPR (unchanged total), bq ring [2][8]=64 VGPR;
// ~195 total regs fits cap 256 spill-free. MFMA count/gather unchanged.
__global__ __launch_bounds__(256, 2)
void edge_mlp3(const unsigned short* __restrict__ hbf,
               const int* __restrict__ dst,
               const int* __restrict__ src,
               const unsigned short* __restrict__ W1F,
               const unsigned short* __restrict__ W2F,
               const unsigned short* __restrict__ W3F,
               float* __restrict__ out) {
  __shared__ __align__(16) unsigned short P[64 * 256];  // dst half; then X, X2
  __shared__ __align__(16) unsigned short S[64 * 256];  // src half
  __shared__ int ioff[128];

  const int t = threadIdx.x, lane = t & 63, w = t >> 6;
  const int lq = lane >> 4, lm = lane & 15;
  const int wr = (w & 1) * 32;        // row base of this wave's output tile
  const int wc = (w >> 1) * 128;      // col base
  const int m0 = blockIdx.x * 64;
  const int mm = lane & 31, rh = lane >> 5, rbase = w * 16;

  if (t < 64)       ioff[t] = dst[m0 + t];
  else if (t < 128) ioff[t] = src[m0 + t - 64];
  __syncthreads();   // ioff visible; nothing else outstanding yet

  // ---- issue BOTH gather halves up-front: dst->P (oldest 8), src->S (newest 8)
#pragma unroll
  for (int tt = 0; tt < 8; ++tt) {
    int rl = rbase + 2 * tt + rh;
    int node = ioff[rl];
    gld16(hbf + (size_t)node * 256 + ((mm ^ sw3(rl)) << 3), &P[(rbase + 2 * tt) * 256]);
  }
#pragma unroll
  for (int tt = 0; tt < 8; ++tt) {
    int rl = rbase + 2 * tt + rh;
    int node = ioff[64 + rl];
    gld16(hbf + (size_t)node * 256 + ((mm ^ sw3(rl)) << 3), &S[(rbase + 2 * tt) * 256]);
  }

  floatx4 acc[2][8];
#pragma unroll
  for (int i = 0; i < 2; ++i)
#pragma unroll
    for (int j = 0; j < 8; ++j) acc[i][j] = (floatx4)(0.0f);

  const short8* B1 = (const short8*)W1F;
  const short8* B2 = (const short8*)W2F;

  // ---- counted wait: this wave's 8 dst loads landed; 8 src stay in flight
  asm volatile("s_waitcnt vmcnt(8)" ::: "memory");
  __builtin_amdgcn_sched_barrier(0);
  __builtin_amdgcn_s_barrier();      // RAW barrier: no vmcnt(0) drain
  __builtin_amdgcn_sched_barrier(0);

  // ---- layer1, k-steps 0..7 (dst features) on P
  {
    short8 bq[2][8];
#pragma unroll
    for (int jt = 0; jt < 8; ++jt) bq[0][jt] = B1[(0 * 256 + wc + jt * 16 + lm) * 4 + lq];
#pragma unroll
    for (int jt = 0; jt < 8; ++jt) bq[1][jt] = B1[(1 * 256 + wc + jt * 16 + lm) * 4 + lq];

#pragma unroll
    for (int s = 0; s < 8; ++s) {
#pragma unroll
      for (int i = 0; i < 2; ++i) {
        int r = wr + i * 16 + lm, c = s * 4 + lq;
        short8 af = *(const short8*)&P[r * 256 + ((c ^ sw3(r)) << 3)];
#pragma unroll
        for (int j = 0; j < 8; ++j)
          acc[i][j] = __builtin_amdgcn_mfma_f32_16x16x32_bf16(af, bq[s & 1][j], acc[i][j], 0, 0, 0);
      }
      if (s < 6)
#pragma unroll
        for (int jt = 0; jt < 8; ++jt)
          bq[s & 1][jt] = B1[((s + 2) * 256 + wc + jt * 16 + lm) * 4 + lq];
    }
  }
  __syncthreads();   // vmcnt(0): src loads (already landed) + barrier

  // ---- layer1, k-steps 8..15 (src features) on S
  {
    short8 bq[2][8];
#pragma unroll
    for (int jt = 0; jt < 8; ++jt) bq[0][jt] = B1[(8 * 256 + wc + jt * 16 + lm) * 4 + lq];
#pragma unroll
    for (int jt = 0; jt < 8; ++jt) bq[1][jt] = B1[(9 * 256 + wc + jt * 16 + lm) * 4 + lq];

#pragma unroll
    for (int s = 0; s < 8; ++s) {
#pragma unroll
      for (int i = 0; i < 2; ++i) {
        int r = wr + i * 16 + lm, c = s * 4 + lq;
        short8 af = *(const short8*)&S[r * 256 + ((c ^ sw3(r)) << 3)];
#pragma unroll
        for (int j = 0; j < 8; ++j)
          acc[i][j] = __builtin_amdgcn_mfma_f32_16x16x32_bf16(af, bq[s & 1][j], acc[i][j], 0, 0, 0);
      }
      if (s < 6)
#pragma unroll
        for (int jt = 0; jt < 8; ++jt)
          bq[s & 1][jt] = B1[((s + 10) * 256 + wc + jt * 16 + lm) * 4 + lq];
    }
  }
  // no barrier needed here: E1 uses only this wave's acc, writes its own
  // (row,col) tile of P, and P's last reads (L1-dst) are barrier-separated.

  // ---- Epilogue 1: relu -> X (=P). C/D map: col=lane&15, row=quad*4+reg
#pragma unroll
  for (int i = 0; i < 2; ++i) {
    int row0 = wr + i * 16 + lq * 4;
#pragma unroll
    for (int j = 0; j < 8; ++j) {
      int col = wc + j * 16 + lm, c8 = col >> 3, ce = col & 7;
#pragma unroll
      for (int rg = 0; rg < 4; ++rg) {
        int row = row0 + rg;
        float v = acc[i][j][rg];
        v = v > 0.0f ? v : 0.0f;
        P[row * 256 + (((c8 ^ sw3(row)) << 3) | ce)] = f2bf(v);
      }
    }
  }
#pragma unroll
  for (int i = 0; i < 2; ++i)
#pragma unroll
    for (int j = 0; j < 8; ++j) acc[i][j] = (floatx4)(0.0f);
  __syncthreads();   // X complete before L2 reads

  // ---- Layer 2: K=256, 8 k-steps, B-ring depth 2, reads X (=P)
  {
    short8 bq[2][8];
#pragma unroll
    for (int jt = 0; jt < 8; ++jt) bq[0][jt] = B2[(0 * 256 + wc + jt * 16 + lm) * 4 + lq];
#pragma unroll
    for (int jt = 0; jt < 8; ++jt) bq[1][jt] = B2[(1 * 256 + wc + jt * 16 + lm) * 4 + lq];

#pragma unroll
    for (int s = 0; s < 8; ++s) {
#pragma unroll
      for (int i = 0; i < 2; ++i) {
        int r = wr + i * 16 + lm, c = s * 4 + lq;
        short8 af = *(const short8*)&P[r * 256 + ((c ^ sw3(r)) << 3)];
#pragma unroll
        for (int j = 0; j < 8; ++j)
          acc[i][j] = __builtin_amdgcn_mfma_f32_16x16x32_bf16(af, bq[s & 1][j], acc[i][j], 0, 0, 0);
      }
      if (s < 6)
#pragma unroll
        for (int jt = 0; jt < 8; ++jt)
          bq[s & 1][jt] = B2[((s + 2) * 256 + wc + jt * 16 + lm) * 4 + lq];
    }
  }
  __syncthreads();   // all X reads done before in-place X2 overwrite

  // ---- Epilogue 2: relu -> X2 (=P, in place)
#pragma unroll
  for (int i = 0; i < 2; ++i) {
    int row0 = wr + i * 16 + lq * 4;
#pragma unroll
    for (int j = 0; j < 8; ++j) {
      int col = wc + j * 16 + lm, c8 = col >> 3, ce = col & 7;
#pragma unroll
      for (int rg = 0; rg < 4; ++rg) {
        int row = row0 + rg;
        float v = acc[i][j][rg];
        v = v > 0.0f ? v : 0.0f;
        P[row * 256 + (((c8 ^ sw3(row)) << 3) | ce)] = f2bf(v);
      }
    }
  }
  __syncthreads();   // X2 complete before L3 reads

  // ---- Layer 3: out = X2 @ W3 via MFMA (N padded to 16; cols 0,1 valid)
  {
    floatx4 a3 = (floatx4)(0.0f);
    const short8* B3 = (const short8*)W3F;
#pragma unroll
    for (int s = 0; s < 8; ++s) {
      short8 b3 = B3[s * 64 + lane];              // 1 KB coalesced, L2-hot
      int r = w * 16 + lm, cch = s * 4 + lq;
      short8 af = *(const short8*)&P[r * 256 + ((cch ^ sw3(r)) << 3)];
      a3 = __builtin_amdgcn_mfma_f32_16x16x32_bf16(af, b3, a3, 0, 0, 0);
    }
    if (lm < 2) {
#pragma unroll
      for (int rg = 0; rg < 4; ++rg)
        out[(m0 + w * 16 + lq * 4 + rg) * 2 + lm] = a3[rg];
    }
  }
}

// ---- legacy weight-frag kernel (fallback path only) ----
__global__ void wfrag_kernel(const float* __restrict__ W,
                             unsigned short* __restrict__ out, int total) {
  int u = blockIdx.x * 256 + threadIdx.x;
  if (u >= total) return;
  int j = u & 7, kq = (u >> 3) & 3, n = (u >> 5) & 255, k32 = u >> 13;
  out[u] = f2bf(W[(k32 * 32 + kq * 8 + j) * 256 + n]);
}

// ---- fp32-gather fallback (tiny workspace) ----
__global__ __launch_bounds__(256, 2)
void edge_mlp_fb(const float* __restrict__ h,
                 const int* __restrict__ dst,
                 const int* __restrict__ src,
                 const unsigned short* __restrict__ W1F,
                 const unsigned short* __restrict__ W2F,
                 const float* __restrict__ W3,
                 float* __restrict__ out) {
  __shared__ unsigned short A[64 * 512];
  __shared__ float w3s[512];
  __shared__ int ioff[128];
  unsigned short* X = A;
  const int t = threadIdx.x, lane = t & 63, w = t >> 6;
  const int lq = lane >> 4, lm = lane & 15;
  const int m0 = blockIdx.x * 64;
  if (t < 64) ioff[t] = dst[m0 + t];
  else if (t < 128) ioff[t] = src[m0 + t - 64];
  w3s[t] = W3[t];
  w3s[t + 256] = W3[t + 256];
  __syncthreads();
  {
    const int c = lane, half = (c >= 32) ? 64 : 0, cc = c & 31;
#pragma unroll
    for (int it = 0; it < 16; ++it) {
      int r = it * 4 + w;
      int node = ioff[half + r];
      const float4* h4 = (const float4*)h;
      float4 v0 = h4[node * 64 + cc * 2], v1 = h4[node * 64 + cc * 2 + 1];
      short8 v;
      v[0] = (short)f2bf(v0.x); v[1] = (short)f2bf(v0.y);
      v[2] = (short)f2bf(v0.z); v[3] = (short)f2bf(v0.w);
      v[4] = (short)f2bf(v1.x); v[5] = (short)f2bf(v1.y);
      v[6] = (short)f2bf(v1.z); v[7] = (short)f2bf(v1.w);
      *(short8*)&A[r * 512 + ((c ^ (r & 7)) << 3)] = v;
    }
  }
  floatx4 acc[4][4];
#pragma unroll
  for (int i = 0; i < 4; ++i)
#pragma unroll
    for (int j = 0; j < 4; ++j) acc[i][j] = (floatx4)(0.0f);
  __syncthreads();
  const short8* B1 = (const short8*)W1F;
  const short8* B2 = (const short8*)W2F;
#pragma unroll
  for (int k32 = 0; k32 < 16; ++k32) {
    short8 b[4], af[4];
#pragma unroll
    for (int jt = 0; jt < 4; ++jt)
      b[jt] = B1[(k32 * 256 + w * 64 + jt * 16 + lm) * 4 + lq];
#pragma unroll
    for (int i = 0; i < 4; ++i) {
      int r = i * 16 + lm, c = k32 * 4 + lq;
      af[i] = *(const short8*)&A[r * 512 + ((c ^ (r & 7)) << 3)];
    }
#pragma unroll
    for (int i = 0; i < 4; ++i)
#pragma unroll
      for (int j = 0; j < 4; ++j)
        acc[i][j] = __builtin_amdgcn_mfma_f32_16x16x32_bf16(af[i], b[j], acc[i][j], 0, 0, 0);
  }
  __syncthreads();
#pragma unroll
  for (int i = 0; i < 4; ++i) {
    int row0 = i * 16 + lq * 4;
#pragma unroll
    for (int j = 0; j < 4; ++j) {
      int col = w * 64 + j * 16 + lm, c8 = col >> 3, ce = col & 7;
#pragma unroll
      for (int rg = 0; rg < 4; ++rg) {
        int row = row0 + rg;
        float v = acc[i][j][rg];
        v = v > 0.0f ? v : 0.0f;
        X[row * 256 + (((c8 ^ (row & 7)) << 3) | ce)] = f2bf(v);
      }
    }
  }
#pragma unroll
  for (int i = 0; i < 4; ++i)
#pragma unroll
    for (int j = 0; j < 4; ++j) acc[i][j] = (floatx4)(0.0f);
  __syncthreads();
#pragma unroll
  for (int k32 = 0; k32 < 8; ++k32) {
    short8 b[4], af[4];
#pragma unroll
    for (int jt = 0; jt < 4; ++jt)
      b[jt] = B2[(k32 * 256 + w * 64 + jt * 16 + lm) * 4 + lq];
#pragma unroll
    for (int i = 0; i < 4; ++i) {
      int r = i * 16 + lm, c = k32 * 4 + lq;
      af[i] = *(const short8*)&X[r * 256 + ((c ^ (r & 7)) << 3)];
    }
#pragma unroll
    for (int i = 0; i < 4; ++i)
#pragma unroll
      for (int j = 0; j < 4; ++j)
        acc[i][j] = __builtin_amdgcn_mfma_f32_16x16x32_bf16(af[i], b[j], acc[i][j], 0, 0, 0);
  }
  __syncthreads();
#pragma unroll
  for (int i = 0; i < 4; ++i) {
    int row0 = i * 16 + lq * 4;
#pragma unroll
    for (int j = 0; j < 4; ++j) {
      int col = w * 64 + j * 16 + lm, c8 = col >> 3, ce = col & 7;
#pragma unroll
      for (int rg = 0; rg < 4; ++rg) {
        int row = row0 + rg;
        float v = acc[i][j][rg];
        v = v > 0.0f ? v : 0.0f;
        X[row * 256 + (((c8 ^ (row & 7)) << 3) | ce)] = f2bf(v);
      }
    }
  }
  __syncthreads();
  {
    int r = t >> 2, o = (t >> 1) & 1, hh = t & 1;
    float s = 0.0f;
#pragma unroll
    for (int it = 0; it < 16; ++it) {
      int c = hh * 16 + it;
      short8 xv = *(const short8*)&X[r * 256 + ((c ^ (r & 7)) << 3)];
#pragma unroll
      for (int e = 0; e < 8; ++e)
        s += bf2f((unsigned short)xv[e]) * w3s[((c << 3) + e) * 2 + o];
    }
    s += __shfl_xor(s, 1);
    if (hh == 0) out[(m0 + r) * 2 + o] = s;
  }
}

extern "C" void kernel_launch(void* const* d_in, const int* in_sizes, int n_in,
                              void* d_out, int out_size, void* d_ws, size_t ws_size,
                              hipStream_t stream) {
  const float* h   = (const float*)d_in[0];
  const int*   dst = (const int*)d_in[1];
  const int*   src = (const int*)d_in[2];
  const float* W1  = (const float*)d_in[3];
  const float* W2  = (const float*)d_in[4];
  const float* W3  = (const float*)d_in[5];
  float* out = (float*)d_out;

  const int h_elems = in_sizes[0];
  const int n_pairs = in_sizes[1];
  const int ntiles  = n_pairs / 64;

  const size_t hbf_elems = (size_t)h_elems;
  const bool use_hbf =
      ws_size >= (hbf_elems + 131072 + 65536 + 4096) * sizeof(unsigned short);

  unsigned short* HBF = (unsigned short*)d_ws;
  unsigned short* W1F = HBF + hbf_elems;
  unsigned short* W2F = W1F + 131072;
  unsigned short* W3F = W2F + 65536;

  if (use_hbf) {
    int nh8 = h_elems / 8;
    int grid = 512 + 256 + 16 + (nh8 + 255) / 256;
    prep_kernel<<<grid, 256, 0, stream>>>(h, W1, W2, W3, HBF, W1F, W2F, W3F, nh8);
    edge_mlp3<<<ntiles, 256, 0, stream>>>(HBF, dst, src, W1F, W2F, W3F, out);
  } else {
    unsigned short* W1Fb = (unsigned short*)d_ws;
    unsigned short* W2Fb = W1Fb + 131072;
    wfrag_kernel<<<512, 256, 0, stream>>>(W1, W1Fb, 131072);
    wfrag_kernel<<<256, 256, 0, stream>>>(W2, W2Fb, 65536);
    edge_mlp_fb<<<ntiles, 256, 0, stream>>>(h, dst, src, W1Fb, W2Fb, W3, out);
  }
}

// Round 11
// 401.083 us; speedup vs baseline: 1.4201x; 1.4201x over previous
//
#include <hip/hip_runtime.h>
#include <stdint.h>

typedef __attribute__((ext_vector_type(8))) short short8;
typedef __attribute__((ext_vector_type(4))) short short4v;
typedef __attribute__((ext_vector_type(4))) float floatx4;

__device__ __forceinline__ unsigned short f2bf(float x) {
  unsigned int u = __float_as_uint(x);
  u += 0x7fffu + ((u >> 16) & 1u);   // RNE
  return (unsigned short)(u >> 16);
}
__device__ __forceinline__ float bf2f(unsigned short b) {
  return __uint_as_float(((unsigned int)b) << 16);
}
// packed pair: two RNE bf16 in one u32 (pure int ops, no asm)
__device__ __forceinline__ unsigned int pk2bf(float lo, float hi) {
  return (unsigned int)f2bf(lo) | ((unsigned int)f2bf(hi) << 16);
}
// row swizzle: spreads same-column reads of consecutive rows across bank-quads.
__device__ __forceinline__ int sw3(int r) { return (r & 7) ^ (((r >> 3) & 1) * 3); }

// direct global->LDS (16B/lane). LDS dest = uniform base + lane*16 (linear);
// swizzle is applied on the per-lane GLOBAL address instead (m173 pattern).
__device__ __forceinline__ void gld16(const unsigned short* g, unsigned short* l) {
  __builtin_amdgcn_global_load_lds(
      (const __attribute__((address_space(1))) void*)g,
      (__attribute__((address_space(3))) void*)l, 16, 0, 0);
}

// ---- unified prologue: weight frags + h bf16 table, fully coalesced ----
// W1F/W2F B-frag layout: u=((k32*256+n)*4+kq)*8+j  holds W[k32*32+kq*8+j][n]
// W3F B-frag layout (N padded 2->16): u=(k32*64+L)*8+j holds W3[k32*32+(L>>4)*8+j][L&15] or 0
__global__ void prep_kernel(const float* __restrict__ h, const float* __restrict__ W1,
                            const float* __restrict__ W2, const float* __restrict__ W3,
                            unsigned short* __restrict__ HBF, unsigned short* __restrict__ W1F,
                            unsigned short* __restrict__ W2F, unsigned short* __restrict__ W3F,
                            int nh8) {
  const int t = threadIdx.x;
  int b = blockIdx.x;
  if (b < 512) {            // W1F: 131072 elems
    int u = b * 256 + t;
    int j = u & 7, kq = (u >> 3) & 3, n = (u >> 5) & 255, k32 = u >> 13;
    W1F[u] = f2bf(W1[(k32 * 32 + kq * 8 + j) * 256 + n]);
    return;
  }
  b -= 512;
  if (b < 256) {            // W2F: 65536 elems
    int u = b * 256 + t;
    int j = u & 7, kq = (u >> 3) & 3, n = (u >> 5) & 255, k32 = u >> 13;
    W2F[u] = f2bf(W2[(k32 * 32 + kq * 8 + j) * 256 + n]);
    return;
  }
  b -= 256;
  if (b < 16) {             // W3F: 4096 elems
    int u = b * 256 + t;
    int j = u & 7, L = (u >> 3) & 63, k32 = u >> 9;
    int n = L & 15, kq = L >> 4;
    W3F[u] = (n < 2) ? f2bf(W3[(k32 * 32 + kq * 8 + j) * 2 + n]) : (unsigned short)0;
    return;
  }
  b -= 16;
  int u = b * 256 + t;      // hcvt: 2x float4 -> 1x short8 (16B stores)
  if (u < nh8) {
    const float4* h4 = (const float4*)h;
    float4 v0 = h4[u * 2], v1 = h4[u * 2 + 1];
    short8 s;
    s[0] = (short)f2bf(v0.x); s[1] = (short)f2bf(v0.y);
    s[2] = (short)f2bf(v0.z); s[3] = (short)f2bf(v0.w);
    s[4] = (short)f2bf(v1.x); s[5] = (short)f2bf(v1.y);
    s[6] = (short)f2bf(v1.z); s[7] = (short)f2bf(v1.w);
    ((short8*)HBF)[u] = s;
  }
}

// ---- main kernel: R3 dual-buffer pipelined K-split + swapped-operand MFMA ----
// Exactly the verified R3 skeleton (4 waves, 256 thr, __launch_bounds__(256,2),
// 64x64 wave tiles, bq[2][4] ring, up-front dual gather, counted vmcnt(8) +
// raw barrier; 291 us, zero spill). Change: layer-1/2 MFMAs swap operands --
// mfma(bq, af, acc) computes (X@W)^T per-fragment, so each lane's 4 C-regs
// are 4 CONSECUTIVE FEATURE COLS of one edge row. Epilogues pack relu'd
// pairs into u32s (pure int ops -- R10's inline-asm v_cvt_pk_bf16_f32 was
// the only novel construct in a kernel that failed the container twice, so
// it is removed) and store 8 B at a time: stores/thread 64 -> 16.
// (R9 lesson: 32x128 retile doubled B-loads and hit the 128-VGPR wall;
// tile geometry stays at R3's optimum.)
__global__ __launch_bounds__(256, 2)
void edge_mlp3(const unsigned short* __restrict__ hbf,
               const int* __restrict__ dst,
               const int* __restrict__ src,
               const unsigned short* __restrict__ W1F,
               const unsigned short* __restrict__ W2F,
               const unsigned short* __restrict__ W3F,
               float* __restrict__ out) {
  __shared__ __align__(16) unsigned short P[64 * 256];  // dst half; then X, X2
  __shared__ __align__(16) unsigned short S[64 * 256];  // src half
  __shared__ int ioff[128];

  const int t = threadIdx.x, lane = t & 63, w = t >> 6;
  const int lq = lane >> 4, lm = lane & 15;
  const int m0 = blockIdx.x * 64;
  const int mm = lane & 31, rh = lane >> 5, rbase = w * 16;

  if (t < 64)       ioff[t] = dst[m0 + t];
  else if (t < 128) ioff[t] = src[m0 + t - 64];
  __syncthreads();   // ioff visible; nothing else outstanding yet

  // ---- issue BOTH gather halves up-front: dst->P (oldest 8), src->S (newest 8)
#pragma unroll
  for (int tt = 0; tt < 8; ++tt) {
    int rl = rbase + 2 * tt + rh;
    int node = ioff[rl];
    gld16(hbf + (size_t)node * 256 + ((mm ^ sw3(rl)) << 3), &P[(rbase + 2 * tt) * 256]);
  }
#pragma unroll
  for (int tt = 0; tt < 8; ++tt) {
    int rl = rbase + 2 * tt + rh;
    int node = ioff[64 + rl];
    gld16(hbf + (size_t)node * 256 + ((mm ^ sw3(rl)) << 3), &S[(rbase + 2 * tt) * 256]);
  }

  floatx4 acc[4][4];
#pragma unroll
  for (int i = 0; i < 4; ++i)
#pragma unroll
    for (int j = 0; j < 4; ++j) acc[i][j] = (floatx4)(0.0f);

  const short8* B1 = (const short8*)W1F;
  const short8* B2 = (const short8*)W2F;

  // ---- counted wait: this wave's 8 dst loads landed; 8 src stay in flight
  asm volatile("s_waitcnt vmcnt(8)" ::: "memory");
  __builtin_amdgcn_sched_barrier(0);
  __builtin_amdgcn_s_barrier();      // RAW barrier: no vmcnt(0) drain
  __builtin_amdgcn_sched_barrier(0);

  // ---- layer1, k-steps 0..7 (dst features) on P; SWAPPED: mfma(bq, af, acc)
  {
    short8 bq[2][4];
#pragma unroll
    for (int jt = 0; jt < 4; ++jt) bq[0][jt] = B1[(0 * 256 + w * 64 + jt * 16 + lm) * 4 + lq];
#pragma unroll
    for (int jt = 0; jt < 4; ++jt) bq[1][jt] = B1[(1 * 256 + w * 64 + jt * 16 + lm) * 4 + lq];

#pragma unroll
    for (int s = 0; s < 8; ++s) {
#pragma unroll
      for (int i = 0; i < 4; ++i) {
        int r = i * 16 + lm, c = s * 4 + lq;
        short8 af = *(const short8*)&P[r * 256 + ((c ^ sw3(r)) << 3)];
#pragma unroll
        for (int j = 0; j < 4; ++j)
          acc[i][j] = __builtin_amdgcn_mfma_f32_16x16x32_bf16(bq[s & 1][j], af, acc[i][j], 0, 0, 0);
      }
      if (s < 6)
#pragma unroll
        for (int jt = 0; jt < 4; ++jt)
          bq[s & 1][jt] = B1[((s + 2) * 256 + w * 64 + jt * 16 + lm) * 4 + lq];
    }
  }
  __syncthreads();   // vmcnt(0): src loads (already landed) + barrier

  // ---- layer1, k-steps 8..15 (src features) on S
  {
    short8 bq[2][4];
#pragma unroll
    for (int jt = 0; jt < 4; ++jt) bq[0][jt] = B1[(8 * 256 + w * 64 + jt * 16 + lm) * 4 + lq];
#pragma unroll
    for (int jt = 0; jt < 4; ++jt) bq[1][jt] = B1[(9 * 256 + w * 64 + jt * 16 + lm) * 4 + lq];

#pragma unroll
    for (int s = 0; s < 8; ++s) {
#pragma unroll
      for (int i = 0; i < 4; ++i) {
        int r = i * 16 + lm, c = s * 4 + lq;
        short8 af = *(const short8*)&S[r * 256 + ((c ^ sw3(r)) << 3)];
#pragma unroll
        for (int j = 0; j < 4; ++j)
          acc[i][j] = __builtin_amdgcn_mfma_f32_16x16x32_bf16(bq[s & 1][j], af, acc[i][j], 0, 0, 0);
      }
      if (s < 6)
#pragma unroll
        for (int jt = 0; jt < 4; ++jt)
          bq[s & 1][jt] = B1[((s + 10) * 256 + w * 64 + jt * 16 + lm) * 4 + lq];
    }
  }
  // no barrier needed here: E1 uses only this wave's acc, writes its own
  // column range of P, and P's last reads (L1-dst) are barrier-separated.

  // ---- Epilogue 1: relu -> X (=P). D^T map: lane holds edge row i*16+lm,
  // 4 consecutive feature cols (w*64 + j*16 + lq*4 + rg). Pack + 8B store.
#pragma unroll
  for (int i = 0; i < 4; ++i) {
    int row = i * 16 + lm;
    int swz = sw3(row);
#pragma unroll
    for (int j = 0; j < 4; ++j) {
      int cb = w * 64 + j * 16 + lq * 4;
      int c8 = cb >> 3, ce = cb & 7;
      float v0 = fmaxf(acc[i][j][0], 0.0f);
      float v1 = fmaxf(acc[i][j][1], 0.0f);
      float v2 = fmaxf(acc[i][j][2], 0.0f);
      float v3 = fmaxf(acc[i][j][3], 0.0f);
      uint2 pv;
      pv.x = pk2bf(v0, v1);
      pv.y = pk2bf(v2, v3);
      *(uint2*)&P[row * 256 + (((c8 ^ swz) << 3) | ce)] = pv;
    }
  }
#pragma unroll
  for (int i = 0; i < 4; ++i)
#pragma unroll
    for (int j = 0; j < 4; ++j) acc[i][j] = (floatx4)(0.0f);
  __syncthreads();   // X complete before L2 reads

  // ---- Layer 2: K=256, 8 k-steps, B-ring depth 2, reads X (=P), swapped
  {
    short8 bq[2][4];
#pragma unroll
    for (int jt = 0; jt < 4; ++jt) bq[0][jt] = B2[(0 * 256 + w * 64 + jt * 16 + lm) * 4 + lq];
#pragma unroll
    for (int jt = 0; jt < 4; ++jt) bq[1][jt] = B2[(1 * 256 + w * 64 + jt * 16 + lm) * 4 + lq];

#pragma unroll
    for (int s = 0; s < 8; ++s) {
#pragma unroll
      for (int i = 0; i < 4; ++i) {
        int r = i * 16 + lm, c = s * 4 + lq;
        short8 af = *(const short8*)&P[r * 256 + ((c ^ sw3(r)) << 3)];
#pragma unroll
        for (int j = 0; j < 4; ++j)
          acc[i][j] = __builtin_amdgcn_mfma_f32_16x16x32_bf16(bq[s & 1][j], af, acc[i][j], 0, 0, 0);
      }
      if (s < 6)
#pragma unroll
        for (int jt = 0; jt < 4; ++jt)
          bq[s & 1][jt] = B2[((s + 2) * 256 + w * 64 + jt * 16 + lm) * 4 + lq];
    }
  }
  __syncthreads();   // all X reads done before in-place X2 overwrite

  // ---- Epilogue 2: relu -> X2 (=P, in place), packed 8B stores
#pragma unroll
  for (int i = 0; i < 4; ++i) {
    int row = i * 16 + lm;
    int swz = sw3(row);
#pragma unroll
    for (int j = 0; j < 4; ++j) {
      int cb = w * 64 + j * 16 + lq * 4;
      int c8 = cb >> 3, ce = cb & 7;
      float v0 = fmaxf(acc[i][j][0], 0.0f);
      float v1 = fmaxf(acc[i][j][1], 0.0f);
      float v2 = fmaxf(acc[i][j][2], 0.0f);
      float v3 = fmaxf(acc[i][j][3], 0.0f);
      uint2 pv;
      pv.x = pk2bf(v0, v1);
      pv.y = pk2bf(v2, v3);
      *(uint2*)&P[row * 256 + (((c8 ^ swz) << 3) | ce)] = pv;
    }
  }
  __syncthreads();   // X2 complete before L3 reads

  // ---- Layer 3: out = X2 @ W3 via MFMA (N padded to 16; cols 0,1 valid)
  // unswapped: D map row=quad*4+reg (edge), col=lane&15 (out idx)
  {
    floatx4 a3 = (floatx4)(0.0f);
    const short8* B3 = (const short8*)W3F;
#pragma unroll
    for (int s = 0; s < 8; ++s) {
      short8 b3 = B3[s * 64 + lane];              // 1 KB coalesced, L2-hot
      int r = w * 16 + lm, cch = s * 4 + lq;
      short8 af = *(const short8*)&P[r * 256 + ((cch ^ sw3(r)) << 3)];
      a3 = __builtin_amdgcn_mfma_f32_16x16x32_bf16(af, b3, a3, 0, 0, 0);
    }
    if (lm < 2) {
#pragma unroll
      for (int rg = 0; rg < 4; ++rg)
        out[(m0 + w * 16 + lq * 4 + rg) * 2 + lm] = a3[rg];
    }
  }
}

// ---- legacy weight-frag kernel (fallback path only) ----
__global__ void wfrag_kernel(const float* __restrict__ W,
                             unsigned short* __restrict__ out, int total) {
  int u = blockIdx.x * 256 + threadIdx.x;
  if (u >= total) return;
  int j = u & 7, kq = (u >> 3) & 3, n = (u >> 5) & 255, k32 = u >> 13;
  out[u] = f2bf(W[(k32 * 32 + kq * 8 + j) * 256 + n]);
}

// ---- fp32-gather fallback (tiny workspace) ----
__global__ __launch_bounds__(256, 2)
void edge_mlp_fb(const float* __restrict__ h,
                 const int* __restrict__ dst,
                 const int* __restrict__ src,
                 const unsigned short* __restrict__ W1F,
                 const unsigned short* __restrict__ W2F,
                 const float* __restrict__ W3,
                 float* __restrict__ out) {
  __shared__ unsigned short A[64 * 512];
  __shared__ float w3s[512];
  __shared__ int ioff[128];
  unsigned short* X = A;
  const int t = threadIdx.x, lane = t & 63, w = t >> 6;
  const int lq = lane >> 4, lm = lane & 15;
  const int m0 = blockIdx.x * 64;
  if (t < 64) ioff[t] = dst[m0 + t];
  else if (t < 128) ioff[t] = src[m0 + t - 64];
  w3s[t] = W3[t];
  w3s[t + 256] = W3[t + 256];
  __syncthreads();
  {
    const int c = lane, half = (c >= 32) ? 64 : 0, cc = c & 31;
#pragma unroll
    for (int it = 0; it < 16; ++it) {
      int r = it * 4 + w;
      int node = ioff[half + r];
      const float4* h4 = (const float4*)h;
      float4 v0 = h4[node * 64 + cc * 2], v1 = h4[node * 64 + cc * 2 + 1];
      short8 v;
      v[0] = (short)f2bf(v0.x); v[1] = (short)f2bf(v0.y);
      v[2] = (short)f2bf(v0.z); v[3] = (short)f2bf(v0.w);
      v[4] = (short)f2bf(v1.x); v[5] = (short)f2bf(v1.y);
      v[6] = (short)f2bf(v1.z); v[7] = (short)f2bf(v1.w);
      *(short8*)&A[r * 512 + ((c ^ (r & 7)) << 3)] = v;
    }
  }
  floatx4 acc[4][4];
#pragma unroll
  for (int i = 0; i < 4; ++i)
#pragma unroll
    for (int j = 0; j < 4; ++j) acc[i][j] = (floatx4)(0.0f);
  __syncthreads();
  const short8* B1 = (const short8*)W1F;
  const short8* B2 = (const short8*)W2F;
#pragma unroll
  for (int k32 = 0; k32 < 16; ++k32) {
    short8 b[4], af[4];
#pragma unroll
    for (int jt = 0; jt < 4; ++jt)
      b[jt] = B1[(k32 * 256 + w * 64 + jt * 16 + lm) * 4 + lq];
#pragma unroll
    for (int i = 0; i < 4; ++i) {
      int r = i * 16 + lm, c = k32 * 4 + lq;
      af[i] = *(const short8*)&A[r * 512 + ((c ^ (r & 7)) << 3)];
    }
#pragma unroll
    for (int i = 0; i < 4; ++i)
#pragma unroll
      for (int j = 0; j < 4; ++j)
        acc[i][j] = __builtin_amdgcn_mfma_f32_16x16x32_bf16(af[i], b[j], acc[i][j], 0, 0, 0);
  }
  __syncthreads();
#pragma unroll
  for (int i = 0; i < 4; ++i) {
    int row0 = i * 16 + lq * 4;
#pragma unroll
    for (int j = 0; j < 4; ++j) {
      int col = w * 64 + j * 16 + lm, c8 = col >> 3, ce = col & 7;
#pragma unroll
      for (int rg = 0; rg < 4; ++rg) {
        int row = row0 + rg;
        float v = acc[i][j][rg];
        v = v > 0.0f ? v : 0.0f;
        X[row * 256 + (((c8 ^ (row & 7)) << 3) | ce)] = f2bf(v);
      }
    }
  }
#pragma unroll
  for (int i = 0; i < 4; ++i)
#pragma unroll
    for (int j = 0; j < 4; ++j) acc[i][j] = (floatx4)(0.0f);
  __syncthreads();
#pragma unroll
  for (int k32 = 0; k32 < 8; ++k32) {
    short8 b[4], af[4];
#pragma unroll
    for (int jt = 0; jt < 4; ++jt)
      b[jt] = B2[(k32 * 256 + w * 64 + jt * 16 + lm) * 4 + lq];
#pragma unroll
    for (int i = 0; i < 4; ++i) {
      int r = i * 16 + lm, c = k32 * 4 + lq;
      af[i] = *(const short8*)&X[r * 256 + ((c ^ (r & 7)) << 3)];
    }
#pragma unroll
    for (int i = 0; i < 4; ++i)
#pragma unroll
      for (int j = 0; j < 4; ++j)
        acc[i][j] = __builtin_amdgcn_mfma_f32_16x16x32_bf16(af[i], b[j], acc[i][j], 0, 0, 0);
  }
  __syncthreads();
#pragma unroll
  for (int i = 0; i < 4; ++i) {
    int row0 = i * 16 + lq * 4;
#pragma unroll
    for (int j = 0; j < 4; ++j) {
      int col = w * 64 + j * 16 + lm, c8 = col >> 3, ce = col & 7;
#pragma unroll
      for (int rg = 0; rg < 4; ++rg) {
        int row = row0 + rg;
        float v = acc[i][j][rg];
        v = v > 0.0f ? v : 0.0f;
        X[row * 256 + (((c8 ^ (row & 7)) << 3) | ce)] = f2bf(v);
      }
    }
  }
  __syncthreads();
  {
    int r = t >> 2, o = (t >> 1) & 1, hh = t & 1;
    float s = 0.0f;
#pragma unroll
    for (int it = 0; it < 16; ++it) {
      int c = hh * 16 + it;
      short8 xv = *(const short8*)&X[r * 256 + ((c ^ (r & 7)) << 3)];
#pragma unroll
      for (int e = 0; e < 8; ++e)
        s += bf2f((unsigned short)xv[e]) * w3s[((c << 3) + e) * 2 + o];
    }
    s += __shfl_xor(s, 1);
    if (hh == 0) out[(m0 + r) * 2 + o] = s;
  }
}

extern "C" void kernel_launch(void* const* d_in, const int* in_sizes, int n_in,
                              void* d_out, int out_size, void* d_ws, size_t ws_size,
                              hipStream_t stream) {
  const float* h   = (const float*)d_in[0];
  const int*   dst = (const int*)d_in[1];
  const int*   src = (const int*)d_in[2];
  const float* W1  = (const float*)d_in[3];
  const float* W2  = (const float*)d_in[4];
  const float* W3  = (const float*)d_in[5];
  float* out = (float*)d_out;

  const int h_elems = in_sizes[0];
  const int n_pairs = in_sizes[1];
  const int ntiles  = n_pairs / 64;

  const size_t hbf_elems = (size_t)h_elems;
  const bool use_hbf =
      ws_size >= (hbf_elems + 131072 + 65536 + 4096) * sizeof(unsigned short);

  unsigned short* HBF = (unsigned short*)d_ws;
  unsigned short* W1F = HBF + hbf_elems;
  unsigned short* W2F = W1F + 131072;
  unsigned short* W3F = W2F + 65536;

  if (use_hbf) {
    int nh8 = h_elems / 8;
    int grid = 512 + 256 + 16 + (nh8 + 255) / 256;
    prep_kernel<<<grid, 256, 0, stream>>>(h, W1, W2, W3, HBF, W1F, W2F, W3F, nh8);
    edge_mlp3<<<ntiles, 256, 0, stream>>>(HBF, dst, src, W1F, W2F, W3F, out);
  } else {
    unsigned short* W1Fb = (unsigned short*)d_ws;
    unsigned short* W2Fb = W1Fb + 131072;
    wfrag_kernel<<<512, 256, 0, stream>>>(W1, W1Fb, 131072);
    wfrag_kernel<<<256, 256, 0, stream>>>(W2, W2Fb, 65536);
    edge_mlp_fb<<<ntiles, 256, 0, stream>>>(h, dst, src, W1Fb, W2Fb, W3, out);
  }
}

// Round 12
// 400.672 us; speedup vs baseline: 1.4215x; 1.0010x over previous
//
#include <hip/hip_runtime.h>
#include <stdint.h>

typedef __attribute__((ext_vector_type(8))) short short8;
typedef __attribute__((ext_vector_type(4))) short short4v;
typedef __attribute__((ext_vector_type(4))) float floatx4;

__device__ __forceinline__ unsigned short f2bf(float x) {
  unsigned int u = __float_as_uint(x);
  u += 0x7fffu + ((u >> 16) & 1u);   // RNE
  return (unsigned short)(u >> 16);
}
__device__ __forceinline__ float bf2f(unsigned short b) {
  return __uint_as_float(((unsigned int)b) << 16);
}
// packed pair: two RNE bf16 in one u32 (pure int ops, no asm)
__device__ __forceinline__ unsigned int pk2bf(float lo, float hi) {
  return (unsigned int)f2bf(lo) | ((unsigned int)f2bf(hi) << 16);
}
// row swizzle: spreads same-column reads of consecutive rows across bank-quads.
__device__ __forceinline__ int sw3(int r) { return (r & 7) ^ (((r >> 3) & 1) * 3); }

// direct global->LDS (16B/lane). LDS dest = uniform base + lane*16 (linear);
// swizzle is applied on the per-lane GLOBAL address instead (m173 pattern).
__device__ __forceinline__ void gld16(const unsigned short* g, unsigned short* l) {
  __builtin_amdgcn_global_load_lds(
      (const __attribute__((address_space(1))) void*)g,
      (__attribute__((address_space(3))) void*)l, 16, 0, 0);
}

// ---- unified prologue: weight frags + h bf16 table, fully coalesced ----
// W1F/W2F B-frag layout: u=((k32*256+n)*4+kq)*8+j  holds W[k32*32+kq*8+j][n]
// W3F B-frag layout (N padded 2->16): u=(k32*64+L)*8+j holds W3[k32*32+(L>>4)*8+j][L&15] or 0
__global__ void prep_kernel(const float* __restrict__ h, const float* __restrict__ W1,
                            const float* __restrict__ W2, const float* __restrict__ W3,
                            unsigned short* __restrict__ HBF, unsigned short* __restrict__ W1F,
                            unsigned short* __restrict__ W2F, unsigned short* __restrict__ W3F,
                            int nh8) {
  const int t = threadIdx.x;
  int b = blockIdx.x;
  if (b < 512) {            // W1F: 131072 elems
    int u = b * 256 + t;
    int j = u & 7, kq = (u >> 3) & 3, n = (u >> 5) & 255, k32 = u >> 13;
    W1F[u] = f2bf(W1[(k32 * 32 + kq * 8 + j) * 256 + n]);
    return;
  }
  b -= 512;
  if (b < 256) {            // W2F: 65536 elems
    int u = b * 256 + t;
    int j = u & 7, kq = (u >> 3) & 3, n = (u >> 5) & 255, k32 = u >> 13;
    W2F[u] = f2bf(W2[(k32 * 32 + kq * 8 + j) * 256 + n]);
    return;
  }
  b -= 256;
  if (b < 16) {             // W3F: 4096 elems
    int u = b * 256 + t;
    int j = u & 7, L = (u >> 3) & 63, k32 = u >> 9;
    int n = L & 15, kq = L >> 4;
    W3F[u] = (n < 2) ? f2bf(W3[(k32 * 32 + kq * 8 + j) * 2 + n]) : (unsigned short)0;
    return;
  }
  b -= 16;
  int u = b * 256 + t;      // hcvt: 2x float4 -> 1x short8 (16B stores)
  if (u < nh8) {
    const float4* h4 = (const float4*)h;
    float4 v0 = h4[u * 2], v1 = h4[u * 2 + 1];
    short8 s;
    s[0] = (short)f2bf(v0.x); s[1] = (short)f2bf(v0.y);
    s[2] = (short)f2bf(v0.z); s[3] = (short)f2bf(v0.w);
    s[4] = (short)f2bf(v1.x); s[5] = (short)f2bf(v1.y);
    s[6] = (short)f2bf(v1.z); s[7] = (short)f2bf(v1.w);
    ((short8*)HBF)[u] = s;
  }
}

// ---- main kernel: R11 (276us) + A-fragment software pipeline ----
// Verified R11 base: 4 waves / 256 thr / __launch_bounds__(256,2), 64x64 wave
// tiles, swapped-operand MFMA (lane holds 4 consecutive feature cols of one
// edge row -> packed 8B epilogue stores), dual-buffer up-front gather with
// counted vmcnt(8) + raw barrier. NEW: the A-frag ds_read_b128s are issued
// one k-step AHEAD (af/afn ring, +32 VGPR of the ~168 headroom at cap 256).
// At 2 waves/SIMD the ~120cyc LDS latency was exposed per k-step (MfmaUtil
// 34%); prefetching hides it under the current step's 16 MFMAs.
__global__ __launch_bounds__(256, 2)
void edge_mlp3(const unsigned short* __restrict__ hbf,
               const int* __restrict__ dst,
               const int* __restrict__ src,
               const unsigned short* __restrict__ W1F,
               const unsigned short* __restrict__ W2F,
               const unsigned short* __restrict__ W3F,
               float* __restrict__ out) {
  __shared__ __align__(16) unsigned short P[64 * 256];  // dst half; then X, X2
  __shared__ __align__(16) unsigned short S[64 * 256];  // src half
  __shared__ int ioff[128];

  const int t = threadIdx.x, lane = t & 63, w = t >> 6;
  const int lq = lane >> 4, lm = lane & 15;
  const int m0 = blockIdx.x * 64;
  const int mm = lane & 31, rh = lane >> 5, rbase = w * 16;

  if (t < 64)       ioff[t] = dst[m0 + t];
  else if (t < 128) ioff[t] = src[m0 + t - 64];
  __syncthreads();   // ioff visible; nothing else outstanding yet

  // ---- issue BOTH gather halves up-front: dst->P (oldest 8), src->S (newest 8)
#pragma unroll
  for (int tt = 0; tt < 8; ++tt) {
    int rl = rbase + 2 * tt + rh;
    int node = ioff[rl];
    gld16(hbf + (size_t)node * 256 + ((mm ^ sw3(rl)) << 3), &P[(rbase + 2 * tt) * 256]);
  }
#pragma unroll
  for (int tt = 0; tt < 8; ++tt) {
    int rl = rbase + 2 * tt + rh;
    int node = ioff[64 + rl];
    gld16(hbf + (size_t)node * 256 + ((mm ^ sw3(rl)) << 3), &S[(rbase + 2 * tt) * 256]);
  }

  floatx4 acc[4][4];
#pragma unroll
  for (int i = 0; i < 4; ++i)
#pragma unroll
    for (int j = 0; j < 4; ++j) acc[i][j] = (floatx4)(0.0f);

  const short8* B1 = (const short8*)W1F;
  const short8* B2 = (const short8*)W2F;

  // ---- counted wait: this wave's 8 dst loads landed; 8 src stay in flight
  asm volatile("s_waitcnt vmcnt(8)" ::: "memory");
  __builtin_amdgcn_sched_barrier(0);
  __builtin_amdgcn_s_barrier();      // RAW barrier: no vmcnt(0) drain
  __builtin_amdgcn_sched_barrier(0);

  // ---- layer1, k-steps 0..7 (dst features) on P; SWAPPED: mfma(bq, af, acc)
  {
    short8 bq[2][4];
#pragma unroll
    for (int jt = 0; jt < 4; ++jt) bq[0][jt] = B1[(0 * 256 + w * 64 + jt * 16 + lm) * 4 + lq];
#pragma unroll
    for (int jt = 0; jt < 4; ++jt) bq[1][jt] = B1[(1 * 256 + w * 64 + jt * 16 + lm) * 4 + lq];

    short8 af[4];
#pragma unroll
    for (int i = 0; i < 4; ++i) {
      int r = i * 16 + lm;
      af[i] = *(const short8*)&P[r * 256 + ((lq ^ sw3(r)) << 3)];
    }
#pragma unroll
    for (int s = 0; s < 8; ++s) {
      short8 afn[4];
      if (s < 7)
#pragma unroll
        for (int i = 0; i < 4; ++i) {
          int r = i * 16 + lm, c = (s + 1) * 4 + lq;
          afn[i] = *(const short8*)&P[r * 256 + ((c ^ sw3(r)) << 3)];
        }
#pragma unroll
      for (int i = 0; i < 4; ++i)
#pragma unroll
        for (int j = 0; j < 4; ++j)
          acc[i][j] = __builtin_amdgcn_mfma_f32_16x16x32_bf16(bq[s & 1][j], af[i], acc[i][j], 0, 0, 0);
      if (s < 6)
#pragma unroll
        for (int jt = 0; jt < 4; ++jt)
          bq[s & 1][jt] = B1[((s + 2) * 256 + w * 64 + jt * 16 + lm) * 4 + lq];
#pragma unroll
      for (int i = 0; i < 4; ++i) af[i] = afn[i];
    }
  }
  __syncthreads();   // vmcnt(0): src loads (already landed) + barrier

  // ---- layer1, k-steps 8..15 (src features) on S
  {
    short8 bq[2][4];
#pragma unroll
    for (int jt = 0; jt < 4; ++jt) bq[0][jt] = B1[(8 * 256 + w * 64 + jt * 16 + lm) * 4 + lq];
#pragma unroll
    for (int jt = 0; jt < 4; ++jt) bq[1][jt] = B1[(9 * 256 + w * 64 + jt * 16 + lm) * 4 + lq];

    short8 af[4];
#pragma unroll
    for (int i = 0; i < 4; ++i) {
      int r = i * 16 + lm;
      af[i] = *(const short8*)&S[r * 256 + ((lq ^ sw3(r)) << 3)];
    }
#pragma unroll
    for (int s = 0; s < 8; ++s) {
      short8 afn[4];
      if (s < 7)
#pragma unroll
        for (int i = 0; i < 4; ++i) {
          int r = i * 16 + lm, c = (s + 1) * 4 + lq;
          afn[i] = *(const short8*)&S[r * 256 + ((c ^ sw3(r)) << 3)];
        }
#pragma unroll
      for (int i = 0; i < 4; ++i)
#pragma unroll
        for (int j = 0; j < 4; ++j)
          acc[i][j] = __builtin_amdgcn_mfma_f32_16x16x32_bf16(bq[s & 1][j], af[i], acc[i][j], 0, 0, 0);
      if (s < 6)
#pragma unroll
        for (int jt = 0; jt < 4; ++jt)
          bq[s & 1][jt] = B1[((s + 10) * 256 + w * 64 + jt * 16 + lm) * 4 + lq];
#pragma unroll
      for (int i = 0; i < 4; ++i) af[i] = afn[i];
    }
  }
  // no barrier needed here: E1 uses only this wave's acc, writes its own
  // column range of P, and P's last reads (L1-dst) are barrier-separated.

  // ---- Epilogue 1: relu -> X (=P). D^T map: lane holds edge row i*16+lm,
  // 4 consecutive feature cols (w*64 + j*16 + lq*4 + rg). Pack + 8B store.
#pragma unroll
  for (int i = 0; i < 4; ++i) {
    int row = i * 16 + lm;
    int swz = sw3(row);
#pragma unroll
    for (int j = 0; j < 4; ++j) {
      int cb = w * 64 + j * 16 + lq * 4;
      int c8 = cb >> 3, ce = cb & 7;
      float v0 = fmaxf(acc[i][j][0], 0.0f);
      float v1 = fmaxf(acc[i][j][1], 0.0f);
      float v2 = fmaxf(acc[i][j][2], 0.0f);
      float v3 = fmaxf(acc[i][j][3], 0.0f);
      uint2 pv;
      pv.x = pk2bf(v0, v1);
      pv.y = pk2bf(v2, v3);
      *(uint2*)&P[row * 256 + (((c8 ^ swz) << 3) | ce)] = pv;
    }
  }
#pragma unroll
  for (int i = 0; i < 4; ++i)
#pragma unroll
    for (int j = 0; j < 4; ++j) acc[i][j] = (floatx4)(0.0f);
  __syncthreads();   // X complete before L2 reads

  // ---- Layer 2: K=256, 8 k-steps, B-ring depth 2, reads X (=P), swapped
  {
    short8 bq[2][4];
#pragma unroll
    for (int jt = 0; jt < 4; ++jt) bq[0][jt] = B2[(0 * 256 + w * 64 + jt * 16 + lm) * 4 + lq];
#pragma unroll
    for (int jt = 0; jt < 4; ++jt) bq[1][jt] = B2[(1 * 256 + w * 64 + jt * 16 + lm) * 4 + lq];

    short8 af[4];
#pragma unroll
    for (int i = 0; i < 4; ++i) {
      int r = i * 16 + lm;
      af[i] = *(const short8*)&P[r * 256 + ((lq ^ sw3(r)) << 3)];
    }
#pragma unroll
    for (int s = 0; s < 8; ++s) {
      short8 afn[4];
      if (s < 7)
#pragma unroll
        for (int i = 0; i < 4; ++i) {
          int r = i * 16 + lm, c = (s + 1) * 4 + lq;
          afn[i] = *(const short8*)&P[r * 256 + ((c ^ sw3(r)) << 3)];
        }
#pragma unroll
      for (int i = 0; i < 4; ++i)
#pragma unroll
        for (int j = 0; j < 4; ++j)
          acc[i][j] = __builtin_amdgcn_mfma_f32_16x16x32_bf16(bq[s & 1][j], af[i], acc[i][j], 0, 0, 0);
      if (s < 6)
#pragma unroll
        for (int jt = 0; jt < 4; ++jt)
          bq[s & 1][jt] = B2[((s + 2) * 256 + w * 64 + jt * 16 + lm) * 4 + lq];
#pragma unroll
      for (int i = 0; i < 4; ++i) af[i] = afn[i];
    }
  }
  __syncthreads();   // all X reads done before in-place X2 overwrite

  // ---- Epilogue 2: relu -> X2 (=P, in place), packed 8B stores
#pragma unroll
  for (int i = 0; i < 4; ++i) {
    int row = i * 16 + lm;
    int swz = sw3(row);
#pragma unroll
    for (int j = 0; j < 4; ++j) {
      int cb = w * 64 + j * 16 + lq * 4;
      int c8 = cb >> 3, ce = cb & 7;
      float v0 = fmaxf(acc[i][j][0], 0.0f);
      float v1 = fmaxf(acc[i][j][1], 0.0f);
      float v2 = fmaxf(acc[i][j][2], 0.0f);
      float v3 = fmaxf(acc[i][j][3], 0.0f);
      uint2 pv;
      pv.x = pk2bf(v0, v1);
      pv.y = pk2bf(v2, v3);
      *(uint2*)&P[row * 256 + (((c8 ^ swz) << 3) | ce)] = pv;
    }
  }
  __syncthreads();   // X2 complete before L3 reads

  // ---- Layer 3: out = X2 @ W3 via MFMA (N padded to 16; cols 0,1 valid)
  // unswapped: D map row=quad*4+reg (edge), col=lane&15 (out idx)
  {
    floatx4 a3 = (floatx4)(0.0f);
    const short8* B3 = (const short8*)W3F;
#pragma unroll
    for (int s = 0; s < 8; ++s) {
      short8 b3 = B3[s * 64 + lane];              // 1 KB coalesced, L2-hot
      int r = w * 16 + lm, cch = s * 4 + lq;
      short8 af = *(const short8*)&P[r * 256 + ((cch ^ sw3(r)) << 3)];
      a3 = __builtin_amdgcn_mfma_f32_16x16x32_bf16(af, b3, a3, 0, 0, 0);
    }
    if (lm < 2) {
#pragma unroll
      for (int rg = 0; rg < 4; ++rg)
        out[(m0 + w * 16 + lq * 4 + rg) * 2 + lm] = a3[rg];
    }
  }
}

// ---- legacy weight-frag kernel (fallback path only) ----
__global__ void wfrag_kernel(const float* __restrict__ W,
                             unsigned short* __restrict__ out, int total) {
  int u = blockIdx.x * 256 + threadIdx.x;
  if (u >= total) return;
  int j = u & 7, kq = (u >> 3) & 3, n = (u >> 5) & 255, k32 = u >> 13;
  out[u] = f2bf(W[(k32 * 32 + kq * 8 + j) * 256 + n]);
}

// ---- fp32-gather fallback (tiny workspace) ----
__global__ __launch_bounds__(256, 2)
void edge_mlp_fb(const float* __restrict__ h,
                 const int* __restrict__ dst,
                 const int* __restrict__ src,
                 const unsigned short* __restrict__ W1F,
                 const unsigned short* __restrict__ W2F,
                 const float* __restrict__ W3,
                 float* __restrict__ out) {
  __shared__ unsigned short A[64 * 512];
  __shared__ float w3s[512];
  __shared__ int ioff[128];
  unsigned short* X = A;
  const int t = threadIdx.x, lane = t & 63, w = t >> 6;
  const int lq = lane >> 4, lm = lane & 15;
  const int m0 = blockIdx.x * 64;
  if (t < 64) ioff[t] = dst[m0 + t];
  else if (t < 128) ioff[t] = src[m0 + t - 64];
  w3s[t] = W3[t];
  w3s[t + 256] = W3[t + 256];
  __syncthreads();
  {
    const int c = lane, half = (c >= 32) ? 64 : 0, cc = c & 31;
#pragma unroll
    for (int it = 0; it < 16; ++it) {
      int r = it * 4 + w;
      int node = ioff[half + r];
      const float4* h4 = (const float4*)h;
      float4 v0 = h4[node * 64 + cc * 2], v1 = h4[node * 64 + cc * 2 + 1];
      short8 v;
      v[0] = (short)f2bf(v0.x); v[1] = (short)f2bf(v0.y);
      v[2] = (short)f2bf(v0.z); v[3] = (short)f2bf(v0.w);
      v[4] = (short)f2bf(v1.x); v[5] = (short)f2bf(v1.y);
      v[6] = (short)f2bf(v1.z); v[7] = (short)f2bf(v1.w);
      *(short8*)&A[r * 512 + ((c ^ (r & 7)) << 3)] = v;
    }
  }
  floatx4 acc[4][4];
#pragma unroll
  for (int i = 0; i < 4; ++i)
#pragma unroll
    for (int j = 0; j < 4; ++j) acc[i][j] = (floatx4)(0.0f);
  __syncthreads();
  const short8* B1 = (const short8*)W1F;
  const short8* B2 = (const short8*)W2F;
#pragma unroll
  for (int k32 = 0; k32 < 16; ++k32) {
    short8 b[4], af[4];
#pragma unroll
    for (int jt = 0; jt < 4; ++jt)
      b[jt] = B1[(k32 * 256 + w * 64 + jt * 16 + lm) * 4 + lq];
#pragma unroll
    for (int i = 0; i < 4; ++i) {
      int r = i * 16 + lm, c = k32 * 4 + lq;
      af[i] = *(const short8*)&A[r * 512 + ((c ^ (r & 7)) << 3)];
    }
#pragma unroll
    for (int i = 0; i < 4; ++i)
#pragma unroll
      for (int j = 0; j < 4; ++j)
        acc[i][j] = __builtin_amdgcn_mfma_f32_16x16x32_bf16(af[i], b[j], acc[i][j], 0, 0, 0);
  }
  __syncthreads();
#pragma unroll
  for (int i = 0; i < 4; ++i) {
    int row0 = i * 16 + lq * 4;
#pragma unroll
    for (int j = 0; j < 4; ++j) {
      int col = w * 64 + j * 16 + lm, c8 = col >> 3, ce = col & 7;
#pragma unroll
      for (int rg = 0; rg < 4; ++rg) {
        int row = row0 + rg;
        float v = acc[i][j][rg];
        v = v > 0.0f ? v : 0.0f;
        X[row * 256 + (((c8 ^ (row & 7)) << 3) | ce)] = f2bf(v);
      }
    }
  }
#pragma unroll
  for (int i = 0; i < 4; ++i)
#pragma unroll
    for (int j = 0; j < 4; ++j) acc[i][j] = (floatx4)(0.0f);
  __syncthreads();
#pragma unroll
  for (int k32 = 0; k32 < 8; ++k32) {
    short8 b[4], af[4];
#pragma unroll
    for (int jt = 0; jt < 4; ++jt)
      b[jt] = B2[(k32 * 256 + w * 64 + jt * 16 + lm) * 4 + lq];
#pragma unroll
    for (int i = 0; i < 4; ++i) {
      int r = i * 16 + lm, c = k32 * 4 + lq;
      af[i] = *(const short8*)&X[r * 256 + ((c ^ (r & 7)) << 3)];
    }
#pragma unroll
    for (int i = 0; i < 4; ++i)
#pragma unroll
      for (int j = 0; j < 4; ++j)
        acc[i][j] = __builtin_amdgcn_mfma_f32_16x16x32_bf16(af[i], b[j], acc[i][j], 0, 0, 0);
  }
  __syncthreads();
#pragma unroll
  for (int i = 0; i < 4; ++i) {
    int row0 = i * 16 + lq * 4;
#pragma unroll
    for (int j = 0; j < 4; ++j) {
      int col = w * 64 + j * 16 + lm, c8 = col >> 3, ce = col & 7;
#pragma unroll
      for (int rg = 0; rg < 4; ++rg) {
        int row = row0 + rg;
        float v = acc[i][j][rg];
        v = v > 0.0f ? v : 0.0f;
        X[row * 256 + (((c8 ^ (row & 7)) << 3) | ce)] = f2bf(v);
      }
    }
  }
  __syncthreads();
  {
    int r = t >> 2, o = (t >> 1) & 1, hh = t & 1;
    float s = 0.0f;
#pragma unroll
    for (int it = 0; it < 16; ++it) {
      int c = hh * 16 + it;
      short8 xv = *(const short8*)&X[r * 256 + ((c ^ (r & 7)) << 3)];
#pragma unroll
      for (int e = 0; e < 8; ++e)
        s += bf2f((unsigned short)xv[e]) * w3s[((c << 3) + e) * 2 + o];
    }
    s += __shfl_xor(s, 1);
    if (hh == 0) out[(m0 + r) * 2 + o] = s;
  }
}

extern "C" void kernel_launch(void* const* d_in, const int* in_sizes, int n_in,
                              void* d_out, int out_size, void* d_ws, size_t ws_size,
                              hipStream_t stream) {
  const float* h   = (const float*)d_in[0];
  const int*   dst = (const int*)d_in[1];
  const int*   src = (const int*)d_in[2];
  const float* W1  = (const float*)d_in[3];
  const float* W2  = (const float*)d_in[4];
  const float* W3  = (const float*)d_in[5];
  float* out = (float*)d_out;

  const int h_elems = in_sizes[0];
  const int n_pairs = in_sizes[1];
  const int ntiles  = n_pairs / 64;

  const size_t hbf_elems = (size_t)h_elems;
  const bool use_hbf =
      ws_size >= (hbf_elems + 131072 + 65536 + 4096) * sizeof(unsigned short);

  unsigned short* HBF = (unsigned short*)d_ws;
  unsigned short* W1F = HBF + hbf_elems;
  unsigned short* W2F = W1F + 131072;
  unsigned short* W3F = W2F + 65536;

  if (use_hbf) {
    int nh8 = h_elems / 8;
    int grid = 512 + 256 + 16 + (nh8 + 255) / 256;
    prep_kernel<<<grid, 256, 0, stream>>>(h, W1, W2, W3, HBF, W1F, W2F, W3F, nh8);
    edge_mlp3<<<ntiles, 256, 0, stream>>>(HBF, dst, src, W1F, W2F, W3F, out);
  } else {
    unsigned short* W1Fb = (unsigned short*)d_ws;
    unsigned short* W2Fb = W1Fb + 131072;
    wfrag_kernel<<<512, 256, 0, stream>>>(W1, W1Fb, 131072);
    wfrag_kernel<<<256, 256, 0, stream>>>(W2, W2Fb, 65536);
    edge_mlp_fb<<<ntiles, 256, 0, stream>>>(h, dst, src, W1Fb, W2Fb, W3, out);
  }
}